// Round 9
// baseline (534.358 us; speedup 1.0000x reference)
//
#include <hip/hip_runtime.h>
#include <hip/hip_bf16.h>

using f32x4  = float          __attribute__((ext_vector_type(4)));
using bf16x8 = __bf16         __attribute__((ext_vector_type(8)));
using u16x8  = unsigned short __attribute__((ext_vector_type(8)));

#define C_CH 512
#define H_IN 37
#define W_IN 50
#define NPOS 1850       // 37*50
#define NROI 512
#define DIN  25088      // 512*49
#define DFC  4096
#define NPAR 84
#define NCLS 21
#define KS1  8          // gemm1 split-K: kChunk 3136, nkt 49 (odd -> tail)
#define KS2  8          // gemm2 split-K: kChunk 512,  nkt 8
#define KSH  8          // head (old kernel): nkt = 8 (8 % 6 == 2 required)

// prep mega-kernel block ranges
#define PB_X  232                 // transpose_x: 29*8
#define PB_WH 2048                // fill_whead: 4096*128/256
#define PB_TOT (PB_X + PB_WH)     // 2280

__device__ __forceinline__ unsigned pack_bf16x2(float a, float b) {
    __hip_bfloat162 h;
    h.x = __float2bfloat16(a);
    h.y = __float2bfloat16(b);
    return *reinterpret_cast<unsigned*>(&h);
}

__device__ __forceinline__ void gload_lds16(const void* src, void* dst) {
    __builtin_amdgcn_global_load_lds(
        (const __attribute__((address_space(1))) void*)src,
        (__attribute__((address_space(3))) void*)dst, 16, 0, 0);
}

// ---------------------------------------------------------------------------
// Fused prep: transpose_x | fill Whp (fp32 [4096][128], Wp||Ws zero-padded).
// ---------------------------------------------------------------------------
__global__ __launch_bounds__(256) void prep_kernel(
        const float* __restrict__ x, float* __restrict__ xt,
        const float* __restrict__ Wp, const float* __restrict__ Ws,
        float* __restrict__ Whp) {
    __shared__ float tile[64][65];
    int b = blockIdx.x;
    int t = threadIdx.x;
    if (b < PB_X) {
        int p0 = (b % 29) * 64;
        int c0 = (b / 29) * 64;
        int tc = t & 63, tr = t >> 6;
#pragma unroll
        for (int i = 0; i < 16; ++i) {
            int r = tr + i * 4;
            int p = p0 + tc;
            float v = 0.f;
            if (p < NPOS) v = x[(size_t)(c0 + r) * NPOS + p];
            tile[r][tc] = v;
        }
        __syncthreads();
#pragma unroll
        for (int i = 0; i < 16; ++i) {
            int rw = tr + i * 4;
            int p = p0 + rw;
            if (p < NPOS) xt[(size_t)p * C_CH + c0 + tc] = tile[tc][rw];
        }
    } else {
        int idx = (b - PB_X) * 256 + t;
        int k = idx >> 7, c = idx & 127;
        float v = 0.f;
        if (c < NPAR) v = Wp[(size_t)k * NPAR + c];
        else if (c < NPAR + NCLS) v = Ws[(size_t)k * NCLS + (c - NPAR)];
        Whp[idx] = v;
    }
}

// ---------------------------------------------------------------------------
// RoI max-pool.  One block (256 thr) per ROI; thread t owns channels 2t,2t+1.
// pooled layout: [n][bin*512 + ch] bf16 (K-permuted; gemm1 permutes W1 rows).
// ---------------------------------------------------------------------------
__global__ __launch_bounds__(256) void roi_pool_kernel(
        const float* __restrict__ xt, const float* __restrict__ rois,
        __hip_bfloat16* __restrict__ pooled) {
    int n = blockIdx.x;
    int t = threadIdx.x;
    float4 rv = reinterpret_cast<const float4*>(rois)[n];
    int x1 = (int)fminf(fmaxf(rintf(rv.x * 0.0625f), 0.f), (float)W_IN);
    int y1 = (int)fminf(fmaxf(rintf(rv.y * 0.0625f), 0.f), (float)H_IN);
    int x2 = (int)fminf(fmaxf(rintf(rv.z * 0.0625f), 0.f), (float)W_IN);
    int y2 = (int)fminf(fmaxf(rintf(rv.w * 0.0625f), 0.f), (float)H_IN);
    bool valid = (x1 < x2) && (y1 < y2);
    unsigned* outp = reinterpret_cast<unsigned*>(pooled) + (size_t)n * (DIN / 2);
    if (!valid) {
        for (int b = 0; b < 49; ++b) outp[b * 256 + t] = 0u;
        return;
    }
    int x2e = min(x2, W_IN - 1), y2e = min(y2, H_IN - 1);
    int Hc = y2e - y1 + 1, Wc = x2e - x1 + 1;
    const float2* base = reinterpret_cast<const float2*>(xt);
    for (int i = 0; i < 7; ++i) {
        int rs = y1 + (i * Hc) / 7;
        int re = y1 + ((i + 1) * Hc + 6) / 7;
        for (int j = 0; j < 7; ++j) {
            int cs = x1 + (j * Wc) / 7;
            int ce = x1 + ((j + 1) * Wc + 6) / 7;
            float m0 = -__builtin_inff(), m1 = -__builtin_inff();
            for (int r = rs; r < re; ++r) {
                const float2* rowp = base + (size_t)r * (W_IN * C_CH / 2) + t;
                for (int c = cs; c < ce; ++c) {
                    float2 v = rowp[c * (C_CH / 2)];
                    m0 = fmaxf(m0, v.x);
                    m1 = fmaxf(m1, v.y);
                }
            }
            outp[(i * 7 + j) * 256 + t] = pack_bf16x2(m0, m1);
        }
    }
}

// ---------------------------------------------------------------------------
// 256x256 8-phase GEMM (m201-template port, fp32-B variant).
// BM=BN=256, BK=64, 8 waves (2M x 4N), per-wave 128x64 out, 16x16x32 MFMA.
// LDS: A/B double-buffered (4 x 32KB = 128KB). A via global_load_lds
// (pre-swizzled source); B fp32 reg-load -> cvt_pk -> swizzled ds_write.
// Per iteration (2 K-tiles): 8 phases of {4-8 ds_read; 16 MFMA} with
// sched_barrier pinning, and 2 sync points of {vmcnt(0) lgkm(0); s_barrier;
// cvt+write B(tau+2); stageA(tau+2); loadB(tau+3)}.  At each sync the only
// in-flight vmem are operands needed immediately; fresh prefetches re-issue
// right after with 4 phases (~2500cyc) of cover.  Cross-wave visibility:
// every wave drains its own gloads/ds_writes (vmcnt/lgkm or phase data-deps)
// BEFORE arriving at a barrier that precedes any consumer read.
// Requires nkt >= 3.  Odd nkt handled by a 4-phase tail on slot0.
// ---------------------------------------------------------------------------
__global__ __launch_bounds__(512, 2) void gemm256_kernel(
        const __hip_bfloat16* __restrict__ A,
        const float* __restrict__ Bf,
        float* __restrict__ Cp,
        int N, int lda, int ldbn, int kChunk, int nMT, int nNT, int Mtot,
        int perm) {
    __shared__ __align__(16) char lA0[32768];
    __shared__ __align__(16) char lA1[32768];
    __shared__ __align__(16) char lB0[32768];
    __shared__ __align__(16) char lB1[32768];

    int q8 = gridDim.x >> 3;
    int bid = (blockIdx.x & 7) * q8 + (blockIdx.x >> 3);
    int mt = bid % nMT;
    int rr = bid / nMT;
    int nt = rr % nNT;
    int ks = rr / nNT;
    int m0 = mt * 256, n0 = nt * 256;
    int k0 = ks * kChunk;
    int t = threadIdx.x;
    int lane = t & 63, wid = t >> 6;
    int wm = wid >> 2, wn = wid & 3;

    // ---- A staging: 4 x 1KB wave-chunks per thread-tile; row += 64 per i
    // keeps the XOR swizzle invariant, so one per-lane base pointer suffices.
    int row0 = wid * 8 + (lane >> 3);
    int col0 = (lane & 7) * 16;
    int sw0  = ((row0 ^ (row0 >> 3)) & 7) << 4;
    const char* srcA0 = (const char*)A + ((size_t)(m0 + row0) * lda + k0) * 2
                        + (col0 ^ sw0);
    size_t aIstep = (size_t)64 * lda * 2;
    int dst0 = wid * 1024 + lane * 16;
    auto stageA = [&](char* buf, int tau) {
        const char* s = srcA0 + (size_t)tau * 128;
#pragma unroll
        for (int i = 0; i < 4; ++i)
            gload_lds16(s + (size_t)i * aIstep, buf + dst0 + i * 8192);
    };

    // ---- B staging: thread owns n-cols lane*4..+3 x k-rows wid*8..+7
    int n4 = lane * 4;
    int rstr = perm ? 49 : 1;
    const float* pB = Bf + n0 + n4;
    int kstep = rstr * ldbn;
    int koff0 = (wid * 8) * kstep;
    f32x4 v[8];
    auto loadB = [&](int tau) {
        int kb = k0 + (tau << 6);
        int rb = perm ? ((kb & 511) * 49 + (kb >> 9)) : kb;
        const float* p0 = pB + (size_t)rb * ldbn + koff0;
#pragma unroll
        for (int p = 0; p < 8; ++p)
            v[p] = *reinterpret_cast<const f32x4*>(p0 + (size_t)p * kstep);
    };
    int woff[4];
#pragma unroll
    for (int j = 0; j < 4; ++j) {
        int row = n4 + j;
        woff[j] = row * 128 + ((wid * 16) ^ (((row ^ (row >> 3)) & 7) << 4));
    }
    auto cvtB = [&](char* buf) {
#pragma unroll
        for (int j = 0; j < 4; ++j) {
            uint4 w;
            w.x = pack_bf16x2(v[0][j], v[1][j]);
            w.y = pack_bf16x2(v[2][j], v[3][j]);
            w.z = pack_bf16x2(v[4][j], v[5][j]);
            w.w = pack_bf16x2(v[6][j], v[7][j]);
            *reinterpret_cast<uint4*>(buf + woff[j]) = w;
        }
    };

    // ---- fragment addresses: swizzle folded into base, XOR'd with kk
    int kb0 = (lane >> 4) << 4;
    int pA[8], pBfr[4];
#pragma unroll
    for (int f = 0; f < 8; ++f) {
        int r = wm * 128 + f * 16 + (lane & 15);
        pA[f] = r * 128 + (((r ^ (r >> 3)) & 7) << 4);
    }
#pragma unroll
    for (int f = 0; f < 4; ++f) {
        int r = wn * 64 + f * 16 + (lane & 15);
        pBfr[f] = r * 128 + (((r ^ (r >> 3)) & 7) << 4);
    }

    f32x4 acc[8][4] = {};
    bf16x8 bfr[4];
    auto phase = [&](const char* bufA, const char* bufB, int q, int ksub,
                     bool ldBf) {
        int kk = kb0 | (ksub << 6);
        if (ldBf) {
#pragma unroll
            for (int f = 0; f < 4; ++f)
                bfr[f] = *reinterpret_cast<const bf16x8*>(bufB + (pBfr[f] ^ kk));
        }
        bf16x8 af[4];
#pragma unroll
        for (int f = 0; f < 4; ++f)
            af[f] = *reinterpret_cast<const bf16x8*>(bufA + (pA[q * 4 + f] ^ kk));
        __builtin_amdgcn_s_setprio(1);
#pragma unroll
        for (int f = 0; f < 4; ++f)
#pragma unroll
            for (int nf = 0; nf < 4; ++nf)
                acc[q * 4 + f][nf] = __builtin_amdgcn_mfma_f32_16x16x32_bf16(
                    af[f], bfr[nf], acc[q * 4 + f][nf], 0, 0, 0);
        __builtin_amdgcn_s_setprio(0);
        __builtin_amdgcn_sched_barrier(0);
    };

    int nkt = kChunk >> 6;           // >= 3 by construction

    // prologue: A(0),A(1) staged; B(0),B(1) cvt'd to LDS; B(2) in flight
    stageA(lA0, 0);
    stageA(lA1, 1);
    loadB(0); cvtB(lB0);
    loadB(1); cvtB(lB1);
    loadB(2);
    asm volatile("s_waitcnt vmcnt(8) lgkmcnt(0)" ::: "memory");  // A0,A1 done
    __builtin_amdgcn_s_barrier();

    int nIter = nkt >> 1;
    for (int i = 0; i < nIter; ++i) {
        int ta = 2 * i;
        phase(lA0, lB0, 0, 0, true);
        phase(lA0, lB0, 1, 0, false);
        phase(lA0, lB0, 0, 1, true);
        phase(lA0, lB0, 1, 1, false);
        asm volatile("s_waitcnt vmcnt(0) lgkmcnt(0)" ::: "memory");
        __builtin_amdgcn_s_barrier();
        if (ta + 2 < nkt) { cvtB(lB0); stageA(lA0, ta + 2); }
        if (ta + 3 < nkt) loadB(ta + 3);
        phase(lA1, lB1, 0, 0, true);
        phase(lA1, lB1, 1, 0, false);
        phase(lA1, lB1, 0, 1, true);
        phase(lA1, lB1, 1, 1, false);
        asm volatile("s_waitcnt vmcnt(0) lgkmcnt(0)" ::: "memory");
        __builtin_amdgcn_s_barrier();
        if (ta + 3 < nkt) { cvtB(lB1); stageA(lA1, ta + 3); }
        if (ta + 4 < nkt) loadB(ta + 4);
    }
    if (nkt & 1) {                    // tail tile nkt-1 lives in slot0
        phase(lA0, lB0, 0, 0, true);
        phase(lA0, lB0, 1, 0, false);
        phase(lA0, lB0, 0, 1, true);
        phase(lA0, lB0, 1, 1, false);
    }

    float* outp = Cp + (size_t)ks * Mtot * N;
    int rb0 = m0 + wm * 128;
    int cb = n0 + wn * 64 + (lane & 15);
    int rl = (lane >> 4) * 4;
#pragma unroll
    for (int mf = 0; mf < 8; ++mf)
#pragma unroll
        for (int nf = 0; nf < 4; ++nf)
#pragma unroll
            for (int r = 0; r < 4; ++r)
                outp[(size_t)(rb0 + mf * 16 + rl + r) * N + cb + nf * 16] =
                    acc[mf][nf][r];
}

// ---------------------------------------------------------------------------
// Old 128x128 kernel (R8 structure, setprio removed per m190) — head only.
// Requires nkt % 6 == 2.
// ---------------------------------------------------------------------------
__global__ __launch_bounds__(256, 2) void gemm_f32b_kernel(
        const __hip_bfloat16* __restrict__ A,
        const float* __restrict__ Bf,
        float* __restrict__ Cp,
        int N, int lda, int ldbn, int kChunk, int nMT, int nNT, int Mtot,
        int perm) {
    __shared__ __align__(16) char lA0[16384];
    __shared__ __align__(16) char lA1[16384];
    __shared__ __align__(16) char lA2[16384];
    __shared__ __align__(16) char lB0[16384];
    __shared__ __align__(16) char lB1[16384];

    int q = gridDim.x >> 3;
    int bid = (blockIdx.x & 7) * q + (blockIdx.x >> 3);
    int mt = bid % nMT;
    int nt = (bid / nMT) % nNT;
    int ks = bid / (nMT * nNT);
    int m0 = mt * 128, n0 = nt * 128;
    int k0 = ks * kChunk;
    int t = threadIdx.x;
    int lane = t & 63, wid = t >> 6;

    const char* srcA[4]; int offA[4];
#pragma unroll
    for (int i = 0; i < 4; ++i) {
        int chunk = i * 4 + wid;
        int p = chunk * 1024 + lane * 16;
        int row = p >> 7;
        int swz = ((row ^ (row >> 3)) & 7) << 4;
        srcA[i] = (const char*)A + ((size_t)(m0 + row) * lda + k0) * 2
                  + ((p & 127) ^ swz);
        offA[i] = chunk * 1024;
    }
    auto stageA = [&](char* buf) {
#pragma unroll
        for (int i = 0; i < 4; ++i) {
            gload_lds16(srcA[i], buf + offA[i]);
            srcA[i] += 128;
        }
    };

    int n4 = (t & 31) * 4;
    int k8 = (t >> 5) * 8;
    int rstr = perm ? 49 : 1;
    const float* pB = Bf + n0 + n4;
    int koff[8];
#pragma unroll
    for (int p = 0; p < 8; ++p) koff[p] = (k8 + p) * rstr * ldbn;
    int woff[4];
#pragma unroll
    for (int j = 0; j < 4; ++j) {
        int row = n4 + j;
        int swz = ((row ^ (row >> 3)) & 7) << 4;
        woff[j] = row * 128 + ((k8 * 2) ^ swz);
    }
    auto loadB = [&](int kt, f32x4 (&v)[8]) {
        int kb = k0 + (kt << 6);
        int rb = perm ? ((kb & 511) * 49 + (kb >> 9)) : kb;
        int rbo = rb * ldbn;
#pragma unroll
        for (int p = 0; p < 8; ++p)
            v[p] = *reinterpret_cast<const f32x4*>(pB + (size_t)(rbo + koff[p]));
    };
    auto cvtB = [&](f32x4 (&v)[8], char* bW) {
#pragma unroll
        for (int j = 0; j < 4; ++j) {
            uint4 w;
            w.x = pack_bf16x2(v[0][j], v[1][j]);
            w.y = pack_bf16x2(v[2][j], v[3][j]);
            w.z = pack_bf16x2(v[4][j], v[5][j]);
            w.w = pack_bf16x2(v[6][j], v[7][j]);
            *reinterpret_cast<uint4*>(bW + woff[j]) = w;
        }
    };

    int wm = wid >> 1, wn = wid & 1;
    int kb0 = (lane >> 4) << 4;
    int roA[4], roB[4], sA[4], sB[4];
#pragma unroll
    for (int f = 0; f < 4; ++f) {
        int ra = wm * 64 + f * 16 + (lane & 15);
        int rb = wn * 64 + f * 16 + (lane & 15);
        roA[f] = ra * 128; sA[f] = ((ra ^ (ra >> 3)) & 7) << 4;
        roB[f] = rb * 128; sB[f] = ((rb ^ (rb >> 3)) & 7) << 4;
    }

    f32x4 acc[4][4] = {};
    auto mfmaStep = [&](const char* bA, const char* bB) {
#pragma unroll
        for (int ksub = 0; ksub < 2; ++ksub) {
            int kk = kb0 | (ksub << 6);
            bf16x8 af[4], bfr[4];
#pragma unroll
            for (int f = 0; f < 4; ++f)
                af[f] = *reinterpret_cast<const bf16x8*>(bA + roA[f] + (kk ^ sA[f]));
#pragma unroll
            for (int f = 0; f < 4; ++f)
                bfr[f] = *reinterpret_cast<const bf16x8*>(bB + roB[f] + (kk ^ sB[f]));
#pragma unroll
            for (int mf = 0; mf < 4; ++mf)
#pragma unroll
                for (int nf = 0; nf < 4; ++nf)
                    acc[mf][nf] = __builtin_amdgcn_mfma_f32_16x16x32_bf16(
                        af[mf], bfr[nf], acc[mf][nf], 0, 0, 0);
        }
    };

    f32x4 sP[8], sQ[8];
    auto body = [&](int kt, char* aR, char* aS,
                    f32x4 (&vC)[8], f32x4 (&vL)[8], char* bR, char* bW) {
        stageA(aS);
        loadB(kt + 2, vL);
        mfmaStep(aR, bR);
        cvtB(vC, bW);
        asm volatile("s_waitcnt lgkmcnt(0)\ns_barrier" ::: "memory");
    };

    int nkt = kChunk >> 6;

    stageA(lA0);
    stageA(lA1);
    loadB(0, sP);
    loadB(1, sQ);
    cvtB(sP, lB0);
    asm volatile("s_waitcnt lgkmcnt(0)\ns_barrier" ::: "memory");

    for (int kt = 0; kt + 2 < nkt; kt += 6) {
        body(kt + 0, lA0, lA2, sQ, sP, lB0, lB1);
        body(kt + 1, lA1, lA0, sP, sQ, lB1, lB0);
        body(kt + 2, lA2, lA1, sQ, sP, lB0, lB1);
        body(kt + 3, lA0, lA2, sP, sQ, lB1, lB0);
        body(kt + 4, lA1, lA0, sQ, sP, lB0, lB1);
        body(kt + 5, lA2, lA1, sP, sQ, lB1, lB0);
    }
    mfmaStep(lA0, lB0);
    cvtB(sQ, lB1);
    asm volatile("s_waitcnt vmcnt(0) lgkmcnt(0)\ns_barrier" ::: "memory");
    mfmaStep(lA1, lB1);

    float* outp = Cp + (size_t)ks * Mtot * N;
    int rbase = m0 + wm * 64;
    int cbase = n0 + wn * 64 + (lane & 15);
    int rl = (lane >> 4) * 4;
#pragma unroll
    for (int mf = 0; mf < 4; ++mf)
#pragma unroll
        for (int nf = 0; nf < 4; ++nf)
#pragma unroll
            for (int r = 0; r < 4; ++r)
                outp[(size_t)(rbase + mf * 16 + rl + r) * N + cbase + nf * 16] =
                    acc[mf][nf][r];
}

// ---------------------------------------------------------------------------
// Sum KS split-K partials + bias, ReLU, convert to bf16.
// ---------------------------------------------------------------------------
__global__ __launch_bounds__(256) void reduce_bias_relu_kernel(
        const float* __restrict__ P, const float* __restrict__ bias,
        __hip_bfloat16* __restrict__ out, int MN, int N, int KS) {
    int idx = blockIdx.x * blockDim.x + threadIdx.x;
    int e0 = idx * 4;
    if (e0 >= MN) return;
    f32x4 s = *reinterpret_cast<const f32x4*>(P + e0);
    for (int k = 1; k < KS; ++k)
        s += *reinterpret_cast<const f32x4*>(P + (size_t)k * MN + e0);
    f32x4 b = *reinterpret_cast<const f32x4*>(bias + (e0 & (N - 1)));
    s += b;
    uint2 pk;
    pk.x = pack_bf16x2(fmaxf(s[0], 0.f), fmaxf(s[1], 0.f));
    pk.y = pack_bf16x2(fmaxf(s[2], 0.f), fmaxf(s[3], 0.f));
    *reinterpret_cast<uint2*>(reinterpret_cast<char*>(out) + (size_t)e0 * 2) = pk;
}

// ---------------------------------------------------------------------------
// Sum KS head partials + bias, scatter to (params, scores) output layout.
// ---------------------------------------------------------------------------
__global__ __launch_bounds__(128) void head_reduce_kernel(
        const float* __restrict__ P, const float* __restrict__ bp,
        const float* __restrict__ bs, float* __restrict__ out, int KS) {
    int n = blockIdx.x, c = threadIdx.x;
    float s = 0.f;
    for (int ks = 0; ks < KS; ++ks)
        s += P[(size_t)ks * NROI * 128 + (size_t)n * 128 + c];
    if (c < NPAR)
        out[(size_t)n * NPAR + c] = s + bp[c];
    else if (c < NPAR + NCLS)
        out[(size_t)NROI * NPAR + (size_t)n * NCLS + (c - NPAR)] = s + bs[c - NPAR];
}

// ---------------------------------------------------------------------------
extern "C" void kernel_launch(void* const* d_in, const int* in_sizes, int n_in,
                              void* d_out, int out_size, void* d_ws, size_t ws_size,
                              hipStream_t stream) {
    const float* x    = (const float*)d_in[0];
    const float* rois = (const float*)d_in[1];
    // d_in[2] roi_index: B=1 -> always 0, unused
    const float* W1 = (const float*)d_in[3];
    const float* b1 = (const float*)d_in[4];
    const float* W2 = (const float*)d_in[5];
    const float* b2 = (const float*)d_in[6];
    const float* Wp = (const float*)d_in[7];
    const float* bp = (const float*)d_in[8];
    const float* Ws = (const float*)d_in[9];
    const float* bs = (const float*)d_in[10];
    float* out = (float*)d_out;

    const size_t MB = 1ull << 20;
    char* ws = (char*)d_ws;
    float*          xt     = (float*)(ws + 0);                  // 3.62 MB
    __hip_bfloat16* pooled = (__hip_bfloat16*)(ws + 4   * MB);  // 24.5 MB
    float*          Whp    = (float*)(ws + 30  * MB);           // 2 MB
    float*          part   = (float*)(ws + 34  * MB);           // 64 MB (KS=8)
    __hip_bfloat16* fc6    = (__hip_bfloat16*)(ws + 104 * MB);  // 4 MB
    __hip_bfloat16* fc7    = (__hip_bfloat16*)(ws + 109 * MB);  // 4 MB

    prep_kernel<<<PB_TOT, 256, 0, stream>>>(x, xt, Wp, Ws, Whp);
    roi_pool_kernel<<<NROI, 256, 0, stream>>>(xt, rois, pooled);

    // fc6 = relu(pooled @ W1 + b1): M=512 N=4096 K=25088; 256 blocks, KS=8
    gemm256_kernel<<<2 * 16 * KS1, 512, 0, stream>>>(
        pooled, W1, part, DFC, DIN, DFC, DIN / KS1, 2, 16, NROI, 1);
    reduce_bias_relu_kernel<<<2048, 256, 0, stream>>>(part, b1, fc6,
                                                      NROI * DFC, DFC, KS1);

    // fc7 = relu(fc6 @ W2 + b2): M=512 N=4096 K=4096; 256 blocks, KS=8
    gemm256_kernel<<<2 * 16 * KS2, 512, 0, stream>>>(
        fc6, W2, part, DFC, DFC, DFC, DFC / KS2, 2, 16, NROI, 0);
    reduce_bias_relu_kernel<<<2048, 256, 0, stream>>>(part, b2, fc7,
                                                      NROI * DFC, DFC, KS2);

    // head = fc7 @ [Wp|Ws]: M=512 N=128(pad from 105) K=4096, KS=8 (nkt=8)
    gemm_f32b_kernel<<<4 * KSH, 256, 0, stream>>>(fc7, Whp, part,
                                                  128, DFC, 128, DFC / KSH,
                                                  4, 1, NROI, 0);
    head_reduce_kernel<<<NROI, 128, 0, stream>>>(part, bp, bs, out, KSH);
}

// Round 10
// 391.973 us; speedup vs baseline: 1.3632x; 1.3632x over previous
//
#include <hip/hip_runtime.h>
#include <hip/hip_bf16.h>

using f32x4  = float          __attribute__((ext_vector_type(4)));
using bf16x8 = __bf16         __attribute__((ext_vector_type(8)));
using u16x8  = unsigned short __attribute__((ext_vector_type(8)));

#define C_CH 512
#define H_IN 37
#define W_IN 50
#define NPOS 1850       // 37*50
#define NROI 512
#define DIN  25088      // 512*49
#define DFC  4096
#define NPAR 84
#define NCLS 21
#define KS1  4          // gemm1: nkt = 6272/64 = 98
#define KS2  4          // gemm2: nkt = 1024/64 = 16
#define KSH  8          // head:  nkt = 512/64  = 8

// prep mega-kernel block ranges
#define PB_X  232                 // transpose_x: 29*8
#define PB_WH 2048                // fill_whead: 4096*128/256
#define PB_TOT (PB_X + PB_WH)     // 2280

__device__ __forceinline__ unsigned pack_bf16x2(float a, float b) {
    __hip_bfloat162 h;
    h.x = __float2bfloat16(a);
    h.y = __float2bfloat16(b);
    return *reinterpret_cast<unsigned*>(&h);
}

__device__ __forceinline__ void gload_lds16(const void* src, void* dst) {
    __builtin_amdgcn_global_load_lds(
        (const __attribute__((address_space(1))) void*)src,
        (__attribute__((address_space(3))) void*)dst, 16, 0, 0);
}

// ---------------------------------------------------------------------------
// Fused prep: transpose_x | fill Whp (fp32 [4096][128], Wp||Ws zero-padded).
// ---------------------------------------------------------------------------
__global__ __launch_bounds__(256) void prep_kernel(
        const float* __restrict__ x, float* __restrict__ xt,
        const float* __restrict__ Wp, const float* __restrict__ Ws,
        float* __restrict__ Whp) {
    __shared__ float tile[64][65];
    int b = blockIdx.x;
    int t = threadIdx.x;
    if (b < PB_X) {
        int p0 = (b % 29) * 64;
        int c0 = (b / 29) * 64;
        int tc = t & 63, tr = t >> 6;
#pragma unroll
        for (int i = 0; i < 16; ++i) {
            int r = tr + i * 4;
            int p = p0 + tc;
            float v = 0.f;
            if (p < NPOS) v = x[(size_t)(c0 + r) * NPOS + p];
            tile[r][tc] = v;
        }
        __syncthreads();
#pragma unroll
        for (int i = 0; i < 16; ++i) {
            int rw = tr + i * 4;
            int p = p0 + rw;
            if (p < NPOS) xt[(size_t)p * C_CH + c0 + tc] = tile[tc][rw];
        }
    } else {
        int idx = (b - PB_X) * 256 + t;
        int k = idx >> 7, c = idx & 127;
        float v = 0.f;
        if (c < NPAR) v = Wp[(size_t)k * NPAR + c];
        else if (c < NPAR + NCLS) v = Ws[(size_t)k * NCLS + (c - NPAR)];
        Whp[idx] = v;
    }
}

// ---------------------------------------------------------------------------
// RoI max-pool.  One block (256 thr) per ROI; thread t owns channels 2t,2t+1.
// pooled layout: [n][bin*512 + ch] bf16 (K-permuted; gemm1 permutes W1 rows).
// ---------------------------------------------------------------------------
__global__ __launch_bounds__(256) void roi_pool_kernel(
        const float* __restrict__ xt, const float* __restrict__ rois,
        __hip_bfloat16* __restrict__ pooled) {
    int n = blockIdx.x;
    int t = threadIdx.x;
    float4 rv = reinterpret_cast<const float4*>(rois)[n];
    int x1 = (int)fminf(fmaxf(rintf(rv.x * 0.0625f), 0.f), (float)W_IN);
    int y1 = (int)fminf(fmaxf(rintf(rv.y * 0.0625f), 0.f), (float)H_IN);
    int x2 = (int)fminf(fmaxf(rintf(rv.z * 0.0625f), 0.f), (float)W_IN);
    int y2 = (int)fminf(fmaxf(rintf(rv.w * 0.0625f), 0.f), (float)H_IN);
    bool valid = (x1 < x2) && (y1 < y2);
    unsigned* outp = reinterpret_cast<unsigned*>(pooled) + (size_t)n * (DIN / 2);
    if (!valid) {
        for (int b = 0; b < 49; ++b) outp[b * 256 + t] = 0u;
        return;
    }
    int x2e = min(x2, W_IN - 1), y2e = min(y2, H_IN - 1);
    int Hc = y2e - y1 + 1, Wc = x2e - x1 + 1;
    const float2* base = reinterpret_cast<const float2*>(xt);
    for (int i = 0; i < 7; ++i) {
        int rs = y1 + (i * Hc) / 7;
        int re = y1 + ((i + 1) * Hc + 6) / 7;
        for (int j = 0; j < 7; ++j) {
            int cs = x1 + (j * Wc) / 7;
            int ce = x1 + ((j + 1) * Wc + 6) / 7;
            float m0 = -__builtin_inff(), m1 = -__builtin_inff();
            for (int r = rs; r < re; ++r) {
                const float2* rowp = base + (size_t)r * (W_IN * C_CH / 2) + t;
                for (int c = cs; c < ce; ++c) {
                    float2 v = rowp[c * (C_CH / 2)];
                    m0 = fmaxf(m0, v.x);
                    m1 = fmaxf(m1, v.y);
                }
            }
            outp[(i * 7 + j) * 256 + t] = pack_bf16x2(m0, m1);
        }
    }
}

// ---------------------------------------------------------------------------
// bf16-A x fp32-B GEMM.  128x128 tile, BK=64, 4 waves (2x2), 16x16x32 MFMA.
// Counted-wait pipeline (per-tile, ONE barrier):
//   lA: 3 x 16KB slots, A staged 2 tiles ahead via global_load_lds
//   lB: 2 x 16KB dbuf; B fp32 reg-prefetched 2 tiles deep (vP/vQ static sets),
//       cvt_pk + swizzled ds_write one tile ahead, placed between MFMA halves
//   barrier wait: vmcnt(12) lgkm(0) -- keeps A(t+2):4 + B(t+3):8 in flight;
//   in-order vmem completion then guarantees A(t+1)/B(t+2) landed.
//   Tail tiles (nothing newly issued) use vmcnt(0) -- required there.
// 6-way unrolled loop (LCM(3 A-slots, 2 B-bufs)) => static reg-set binding.
// LDS XOR swizzle ((r^(r>>3))&7)<<4 on 16B slots, both sides.  Requires
// nkt >= 3.  perm=1: B row k' = bin*512+ch from source row ch*49+bin.
// Cp: [KS][Mtot][N] fp32 split-K partials.  XCD-chunked block swizzle.
// ---------------------------------------------------------------------------
__global__ __launch_bounds__(256, 2) void gemm_f32b_kernel(
        const __hip_bfloat16* __restrict__ A,
        const float* __restrict__ Bf,
        float* __restrict__ Cp,
        int N, int lda, int ldbn, int kChunk, int nMT, int nNT, int Mtot,
        int perm) {
    __shared__ __align__(16) char lA[3 * 16384];
    __shared__ __align__(16) char lB[2 * 16384];

    int q = gridDim.x >> 3;
    int bid = (blockIdx.x & 7) * q + (blockIdx.x >> 3);
    int mt = bid % nMT;
    int nt = (bid / nMT) % nNT;
    int ks = bid / (nMT * nNT);
    int m0 = mt * 128, n0 = nt * 128;
    int k0 = ks * kChunk;
    int t = threadIdx.x;
    int lane = t & 63, wid = t >> 6;

    // A staging: pre-swizzled global source, linear LDS dest within a slot
    const char* srcA[4]; int offA[4];
#pragma unroll
    for (int i = 0; i < 4; ++i) {
        int chunk = i * 4 + wid;
        int p = chunk * 1024 + lane * 16;
        int row = p >> 7;
        int swz = ((row ^ (row >> 3)) & 7) << 4;
        srcA[i] = (const char*)A + ((size_t)(m0 + row) * lda + k0) * 2
                  + ((p & 127) ^ swz);
        offA[i] = chunk * 1024;
    }
    auto stageA = [&](char* slot) {      // consecutive calls advance one tile
#pragma unroll
        for (int i = 0; i < 4; ++i) {
            gload_lds16(srcA[i], slot + offA[i]);
            srcA[i] += 128;
        }
    };

    // B: thread owns (n4..n4+3) x (k8..k8+7)
    int n4 = (t & 31) * 4;
    int k8 = (t >> 5) * 8;
    int rstr = perm ? 49 : 1;
    const float* pB = Bf + n0 + n4;
    int koff[8];
#pragma unroll
    for (int p = 0; p < 8; ++p) koff[p] = (k8 + p) * rstr * ldbn;
    int woff[4];
#pragma unroll
    for (int j = 0; j < 4; ++j) {
        int row = n4 + j;
        int swz = ((row ^ (row >> 3)) & 7) << 4;
        woff[j] = row * 128 + ((k8 * 2) ^ swz);
    }
    auto loadB = [&](int kt, f32x4 (&v)[8]) {
        int kb = k0 + (kt << 6);
        int rb = perm ? ((kb & 511) * 49 + (kb >> 9)) : kb;
        int rbo = rb * ldbn;
#pragma unroll
        for (int p = 0; p < 8; ++p)
            v[p] = *reinterpret_cast<const f32x4*>(pB + (size_t)(rbo + koff[p]));
    };
    auto cvtB = [&](f32x4 (&v)[8], char* bW) {
#pragma unroll
        for (int j = 0; j < 4; ++j) {
            uint4 w;
            w.x = pack_bf16x2(v[0][j], v[1][j]);
            w.y = pack_bf16x2(v[2][j], v[3][j]);
            w.z = pack_bf16x2(v[4][j], v[5][j]);
            w.w = pack_bf16x2(v[6][j], v[7][j]);
            *reinterpret_cast<uint4*>(bW + woff[j]) = w;
        }
    };

    // fragment read offsets
    int wm = wid >> 1, wn = wid & 1;
    int kb0 = (lane >> 4) << 4;
    int roA[4], roB[4], sA[4], sB[4];
#pragma unroll
    for (int f = 0; f < 4; ++f) {
        int ra = wm * 64 + f * 16 + (lane & 15);
        int rb = wn * 64 + f * 16 + (lane & 15);
        roA[f] = ra * 128; sA[f] = ((ra ^ (ra >> 3)) & 7) << 4;
        roB[f] = rb * 128; sB[f] = ((rb ^ (rb >> 3)) & 7) << 4;
    }

    f32x4 acc[4][4] = {};
    auto mfmaHalf = [&](const char* bA, const char* bB, int ksub) {
        int kk = kb0 | (ksub << 6);
        bf16x8 af[4], bfr[4];
#pragma unroll
        for (int f = 0; f < 4; ++f)
            af[f] = *reinterpret_cast<const bf16x8*>(bA + roA[f] + (kk ^ sA[f]));
#pragma unroll
        for (int f = 0; f < 4; ++f)
            bfr[f] = *reinterpret_cast<const bf16x8*>(bB + roB[f] + (kk ^ sB[f]));
#pragma unroll
        for (int mf = 0; mf < 4; ++mf)
#pragma unroll
            for (int nf = 0; nf < 4; ++nf)
                acc[mf][nf] = __builtin_amdgcn_mfma_f32_16x16x32_bf16(
                    af[mf], bfr[nf], acc[mf][nf], 0, 0, 0);
    };

    int nkt = kChunk >> 6;               // >= 3 required

    f32x4 vP[8], vQ[8];
    // body(tile tt): compute on (aR,bR); cvt B(tt+1) -> bW; stage A(tt+2);
    // load B(tt+3) into the set just consumed by the cvt.
    auto body = [&](int tt, char* aR, char* aS,
                    f32x4 (&vC)[8], char* bR, char* bW) {
        mfmaHalf(aR, bR, 0);
        if (tt + 1 < nkt) cvtB(vC, bW);          // ds_writes, lgkm-tracked
        mfmaHalf(aR, bR, 1);
        if (tt + 2 < nkt) stageA(aS);            // 4 gloads -> in flight
        if (tt + 3 < nkt) {
            loadB(tt + 3, vC);                   // 8 loads  -> in flight
            asm volatile("s_waitcnt vmcnt(12) lgkmcnt(0)\ns_barrier" ::: "memory");
        } else {
            asm volatile("s_waitcnt vmcnt(0) lgkmcnt(0)\ns_barrier" ::: "memory");
        }
    };

    // prologue: A(0)->s0, A(1)->s1; B0->vP -> lB0 (auto-drains A0,A1,B0 via
    // in-order vmcnt on the cvt's reg dep); B1->vQ; B2->vP in flight.
    stageA(lA);
    stageA(lA + 16384);
    loadB(0, vP);
    loadB(1, vQ);
    cvtB(vP, lB);
    loadB(2, vP);
    asm volatile("s_waitcnt vmcnt(12) lgkmcnt(0)\ns_barrier" ::: "memory");

    char* s0 = lA;  char* s1 = lA + 16384;  char* s2 = lA + 32768;
    char* b0 = lB;  char* b1 = lB + 16384;
    for (int kt = 0; kt < nkt; kt += 6) {
        body(kt + 0, s0, s2, vQ, b0, b1);
        if (kt + 1 < nkt) body(kt + 1, s1, s0, vP, b1, b0);
        if (kt + 2 < nkt) body(kt + 2, s2, s1, vQ, b0, b1);
        if (kt + 3 < nkt) body(kt + 3, s0, s2, vP, b1, b0);
        if (kt + 4 < nkt) body(kt + 4, s1, s0, vQ, b0, b1);
        if (kt + 5 < nkt) body(kt + 5, s2, s1, vP, b1, b0);
    }

    float* outp = Cp + (size_t)ks * Mtot * N;
    int rbase = m0 + wm * 64;
    int cbase = n0 + wn * 64 + (lane & 15);
    int rl = (lane >> 4) * 4;
#pragma unroll
    for (int mf = 0; mf < 4; ++mf)
#pragma unroll
        for (int nf = 0; nf < 4; ++nf)
#pragma unroll
            for (int r = 0; r < 4; ++r)
                outp[(size_t)(rbase + mf * 16 + rl + r) * N + cbase + nf * 16] =
                    acc[mf][nf][r];
}

// ---------------------------------------------------------------------------
// Sum KS split-K partials + bias, ReLU, convert to bf16.
// ---------------------------------------------------------------------------
__global__ __launch_bounds__(256) void reduce_bias_relu_kernel(
        const float* __restrict__ P, const float* __restrict__ bias,
        __hip_bfloat16* __restrict__ out, int MN, int N, int KS) {
    int idx = blockIdx.x * blockDim.x + threadIdx.x;
    int e0 = idx * 4;
    if (e0 >= MN) return;
    f32x4 s = *reinterpret_cast<const f32x4*>(P + e0);
    for (int k = 1; k < KS; ++k)
        s += *reinterpret_cast<const f32x4*>(P + (size_t)k * MN + e0);
    f32x4 b = *reinterpret_cast<const f32x4*>(bias + (e0 & (N - 1)));
    s += b;
    uint2 pk;
    pk.x = pack_bf16x2(fmaxf(s[0], 0.f), fmaxf(s[1], 0.f));
    pk.y = pack_bf16x2(fmaxf(s[2], 0.f), fmaxf(s[3], 0.f));
    *reinterpret_cast<uint2*>(reinterpret_cast<char*>(out) + (size_t)e0 * 2) = pk;
}

// ---------------------------------------------------------------------------
// Sum KS head partials + bias, scatter to (params, scores) output layout.
// ---------------------------------------------------------------------------
__global__ __launch_bounds__(128) void head_reduce_kernel(
        const float* __restrict__ P, const float* __restrict__ bp,
        const float* __restrict__ bs, float* __restrict__ out, int KS) {
    int n = blockIdx.x, c = threadIdx.x;
    float s = 0.f;
    for (int ks = 0; ks < KS; ++ks)
        s += P[(size_t)ks * NROI * 128 + (size_t)n * 128 + c];
    if (c < NPAR)
        out[(size_t)n * NPAR + c] = s + bp[c];
    else if (c < NPAR + NCLS)
        out[(size_t)NROI * NPAR + (size_t)n * NCLS + (c - NPAR)] = s + bs[c - NPAR];
}

// ---------------------------------------------------------------------------
extern "C" void kernel_launch(void* const* d_in, const int* in_sizes, int n_in,
                              void* d_out, int out_size, void* d_ws, size_t ws_size,
                              hipStream_t stream) {
    const float* x    = (const float*)d_in[0];
    const float* rois = (const float*)d_in[1];
    // d_in[2] roi_index: B=1 -> always 0, unused
    const float* W1 = (const float*)d_in[3];
    const float* b1 = (const float*)d_in[4];
    const float* W2 = (const float*)d_in[5];
    const float* b2 = (const float*)d_in[6];
    const float* Wp = (const float*)d_in[7];
    const float* bp = (const float*)d_in[8];
    const float* Ws = (const float*)d_in[9];
    const float* bs = (const float*)d_in[10];
    float* out = (float*)d_out;

    const size_t MB = 1ull << 20;
    char* ws = (char*)d_ws;
    float*          xt     = (float*)(ws + 0);                  // 3.62 MB
    __hip_bfloat16* pooled = (__hip_bfloat16*)(ws + 4   * MB);  // 24.5 MB
    float*          Whp    = (float*)(ws + 30  * MB);           // 2 MB
    float*          part   = (float*)(ws + 34  * MB);           // 32 MB
    __hip_bfloat16* fc6    = (__hip_bfloat16*)(ws + 104 * MB);  // 4 MB
    __hip_bfloat16* fc7    = (__hip_bfloat16*)(ws + 109 * MB);  // 4 MB

    prep_kernel<<<PB_TOT, 256, 0, stream>>>(x, xt, Wp, Ws, Whp);
    roi_pool_kernel<<<NROI, 256, 0, stream>>>(xt, rois, pooled);

    // fc6 = relu(pooled @ W1 + b1):  M=512 N=4096 K=25088, KS=4 (nkt=98), perm
    gemm_f32b_kernel<<<4 * 32 * KS1, 256, 0, stream>>>(
        pooled, W1, part, DFC, DIN, DFC, DIN / KS1, 4, 32, NROI, 1);
    reduce_bias_relu_kernel<<<2048, 256, 0, stream>>>(part, b1, fc6,
                                                      NROI * DFC, DFC, KS1);

    // fc7 = relu(fc6 @ W2 + b2):  M=512 N=4096 K=4096, KS=4 (nkt=16)
    gemm_f32b_kernel<<<4 * 32 * KS2, 256, 0, stream>>>(
        fc6, W2, part, DFC, DFC, DFC, DFC / KS2, 4, 32, NROI, 0);
    reduce_bias_relu_kernel<<<2048, 256, 0, stream>>>(part, b2, fc7,
                                                      NROI * DFC, DFC, KS2);

    // head = fc7 @ [Wp|Ws]:  M=512 N=128(pad from 105) K=4096, KS=8 (nkt=8)
    gemm_f32b_kernel<<<4 * KSH, 256, 0, stream>>>(fc7, Whp, part,
                                                  128, DFC, 128, DFC / KSH,
                                                  4, 1, NROI, 0);
    head_reduce_kernel<<<NROI, 128, 0, stream>>>(part, bp, bs, out, KSH);
}

// Round 11
// 374.959 us; speedup vs baseline: 1.4251x; 1.0454x over previous
//
#include <hip/hip_runtime.h>
#include <hip/hip_bf16.h>

using f32x4  = float          __attribute__((ext_vector_type(4)));
using bf16x8 = __bf16         __attribute__((ext_vector_type(8)));
using u16x8  = unsigned short __attribute__((ext_vector_type(8)));

#define C_CH 512
#define H_IN 37
#define W_IN 50
#define NPOS 1850       // 37*50
#define NROI 512
#define DIN  25088      // 512*49
#define DFC  4096
#define NPAR 84
#define NCLS 21
#define KS1  8          // gemm1: kChunk 3136, nkt 49 (odd -> tail)
#define KS2  8          // gemm2: kChunk 512,  nkt 8
#define KSH  8          // head (128^2 kernel): nkt 8

// prep mega-kernel block ranges
#define PB_X  232                 // transpose_x: 29*8
#define PB_WH 2048                // fill_whead: 4096*128/256
#define PB_TOT (PB_X + PB_WH)     // 2280

__device__ __forceinline__ unsigned pack_bf16x2(float a, float b) {
    __hip_bfloat162 h;
    h.x = __float2bfloat16(a);
    h.y = __float2bfloat16(b);
    return *reinterpret_cast<unsigned*>(&h);
}

__device__ __forceinline__ void gload_lds16(const void* src, void* dst) {
    __builtin_amdgcn_global_load_lds(
        (const __attribute__((address_space(1))) void*)src,
        (__attribute__((address_space(3))) void*)dst, 16, 0, 0);
}

// ---------------------------------------------------------------------------
// Fused prep: transpose_x | fill Whp (fp32 [4096][128], Wp||Ws zero-padded).
// ---------------------------------------------------------------------------
__global__ __launch_bounds__(256) void prep_kernel(
        const float* __restrict__ x, float* __restrict__ xt,
        const float* __restrict__ Wp, const float* __restrict__ Ws,
        float* __restrict__ Whp) {
    __shared__ float tile[64][65];
    int b = blockIdx.x;
    int t = threadIdx.x;
    if (b < PB_X) {
        int p0 = (b % 29) * 64;
        int c0 = (b / 29) * 64;
        int tc = t & 63, tr = t >> 6;
#pragma unroll
        for (int i = 0; i < 16; ++i) {
            int r = tr + i * 4;
            int p = p0 + tc;
            float v = 0.f;
            if (p < NPOS) v = x[(size_t)(c0 + r) * NPOS + p];
            tile[r][tc] = v;
        }
        __syncthreads();
#pragma unroll
        for (int i = 0; i < 16; ++i) {
            int rw = tr + i * 4;
            int p = p0 + rw;
            if (p < NPOS) xt[(size_t)p * C_CH + c0 + tc] = tile[tc][rw];
        }
    } else {
        int idx = (b - PB_X) * 256 + t;
        int k = idx >> 7, c = idx & 127;
        float v = 0.f;
        if (c < NPAR) v = Wp[(size_t)k * NPAR + c];
        else if (c < NPAR + NCLS) v = Ws[(size_t)k * NCLS + (c - NPAR)];
        Whp[idx] = v;
    }
}

// ---------------------------------------------------------------------------
// RoI max-pool.  One block (256 thr) per ROI; thread t owns channels 2t,2t+1.
// pooled layout: [n][bin*512 + ch] bf16 (K-permuted; gemm1 permutes W1 rows).
// ---------------------------------------------------------------------------
__global__ __launch_bounds__(256) void roi_pool_kernel(
        const float* __restrict__ xt, const float* __restrict__ rois,
        __hip_bfloat16* __restrict__ pooled) {
    int n = blockIdx.x;
    int t = threadIdx.x;
    float4 rv = reinterpret_cast<const float4*>(rois)[n];
    int x1 = (int)fminf(fmaxf(rintf(rv.x * 0.0625f), 0.f), (float)W_IN);
    int y1 = (int)fminf(fmaxf(rintf(rv.y * 0.0625f), 0.f), (float)H_IN);
    int x2 = (int)fminf(fmaxf(rintf(rv.z * 0.0625f), 0.f), (float)W_IN);
    int y2 = (int)fminf(fmaxf(rintf(rv.w * 0.0625f), 0.f), (float)H_IN);
    bool valid = (x1 < x2) && (y1 < y2);
    unsigned* outp = reinterpret_cast<unsigned*>(pooled) + (size_t)n * (DIN / 2);
    if (!valid) {
        for (int b = 0; b < 49; ++b) outp[b * 256 + t] = 0u;
        return;
    }
    int x2e = min(x2, W_IN - 1), y2e = min(y2, H_IN - 1);
    int Hc = y2e - y1 + 1, Wc = x2e - x1 + 1;
    const float2* base = reinterpret_cast<const float2*>(xt);
    for (int i = 0; i < 7; ++i) {
        int rs = y1 + (i * Hc) / 7;
        int re = y1 + ((i + 1) * Hc + 6) / 7;
        for (int j = 0; j < 7; ++j) {
            int cs = x1 + (j * Wc) / 7;
            int ce = x1 + ((j + 1) * Wc + 6) / 7;
            float m0 = -__builtin_inff(), m1 = -__builtin_inff();
            for (int r = rs; r < re; ++r) {
                const float2* rowp = base + (size_t)r * (W_IN * C_CH / 2) + t;
                for (int c = cs; c < ce; ++c) {
                    float2 v = rowp[c * (C_CH / 2)];
                    m0 = fmaxf(m0, v.x);
                    m1 = fmaxf(m1, v.y);
                }
            }
            outp[(i * 7 + j) * 256 + t] = pack_bf16x2(m0, m1);
        }
    }
}

// ---------------------------------------------------------------------------
// 256x256 8-phase GEMM (m201 template, fp32-B variant, counted vmcnt).
// BM=BN=256, BK=64, 8 waves (2M x 4N), per-wave 128x64, 16x16x32 MFMA.
// LDS 128KB: lA[2]/lB[2] x 32KB.  Per 2-tile iteration, 8 phases of
// {ds_read frags | staging slice | s_barrier | lgkm(0)+sched_barrier |
//  setprio(1) 16 MFMA setprio(0) | s_barrier}.
// Staging plan (iter i, t0=2i):  ph0: cvt B(t0+1)->lB1 + A-DMA(t0+1)x2;
// ph1: A-DMA(t0+1)x2 + Bload(t0+2)x4; ph2: Bload(t0+2)x4; ph3: [vmcnt(0)];
// ph4: cvt B(t0+2)->lB0 + A-DMA(t0+2)x2; ph5: A-DMA(t0+2)x2;
// ph6: Bload(t0+3)x4; ph7: Bload(t0+3)x4 + [vmcnt(8): A done, B flies].
// Odd nkt: staging-free 4-phase tail on buffers 0.  Prefetch tiles clamped.
// perm=1: B row k' = bin*512+ch from source row ch*49+bin (RoI-k permute).
// Cp: [KS][Mtot][N] fp32 split-K partials.  XCD-chunked block swizzle
// (grid % 8 == 0).
// ---------------------------------------------------------------------------
__global__ __launch_bounds__(512) void gemm256_kernel(
        const __hip_bfloat16* __restrict__ A,
        const float* __restrict__ Bf,
        float* __restrict__ Cp,
        int N, int lda, int ldbn, int kChunk, int nMT, int nNT, int Mtot,
        int perm) {
    __shared__ __align__(16) char lA0[32768];
    __shared__ __align__(16) char lA1[32768];
    __shared__ __align__(16) char lB0[32768];
    __shared__ __align__(16) char lB1[32768];

    int q8 = gridDim.x >> 3;
    int bid = (blockIdx.x & 7) * q8 + (blockIdx.x >> 3);
    int mt = bid % nMT;
    int rr = bid / nMT;
    int nt = rr % nNT;
    int ks = rr / nNT;
    int m0 = mt * 256, n0 = nt * 256;
    int k0 = ks * kChunk;
    int t = threadIdx.x;
    int lane = t & 63, wid = t >> 6;
    int wm = wid >> 2, wn = wid & 3;
    int nkt = kChunk >> 6;

    // ---- A staging: thread covers rows {o*64 + (t>>3)}, col (t&7)*16, 4 ops
    int rowA = t >> 3;
    int colA = (t & 7) * 16;
    int swA  = ((rowA ^ (rowA >> 3)) & 7) << 4;
    const char* srcA0 = (const char*)A + ((size_t)(m0 + rowA) * lda + k0) * 2
                        + (colA ^ swA);
    size_t aIstep = (size_t)64 * lda * 2;      // row += 64 keeps swizzle bits
    int dstA0 = t * 16;
    auto stageA2 = [&](char* buf, int tau, int half) {
        if (tau >= nkt) tau = nkt - 1;
        const char* s = srcA0 + (size_t)tau * 128;
#pragma unroll
        for (int i = half * 2; i < half * 2 + 2; ++i)
            gload_lds16(s + (size_t)i * aIstep, buf + dstA0 + i * 8192);
    };

    // ---- B staging: thread owns n-cols (t&63)*4..+3 x k-rows (t>>6)*8..+7
    int n4 = (t & 63) * 4;
    int k8 = (t >> 6) * 8;
    int rstr = perm ? 49 : 1;
    const float* pB = Bf + n0 + n4;
    int kstep = rstr * ldbn;
    f32x4 v[8];
    auto loadB4 = [&](int tau, int half) {
        if (tau >= nkt) tau = nkt - 1;
        int kb = k0 + (tau << 6);
        int rb = perm ? ((kb & 511) * 49 + (kb >> 9)) : kb;
        const float* p0 = pB + (size_t)rb * ldbn + (size_t)k8 * kstep;
#pragma unroll
        for (int p = half * 4; p < half * 4 + 4; ++p)
            v[p] = *reinterpret_cast<const f32x4*>(p0 + (size_t)p * kstep);
    };
    int woff[4];
#pragma unroll
    for (int j = 0; j < 4; ++j) {
        int row = n4 + j;
        woff[j] = row * 128 + ((k8 * 2) ^ (((row ^ (row >> 3)) & 7) << 4));
    }
    auto cvtB = [&](char* buf) {
#pragma unroll
        for (int j = 0; j < 4; ++j) {
            uint4 w;
            w.x = pack_bf16x2(v[0][j], v[1][j]);
            w.y = pack_bf16x2(v[2][j], v[3][j]);
            w.z = pack_bf16x2(v[4][j], v[5][j]);
            w.w = pack_bf16x2(v[6][j], v[7][j]);
            *reinterpret_cast<uint4*>(buf + woff[j]) = w;
        }
    };

    // ---- fragment addresses (swizzle folded into base; XOR with kk)
    int kb0 = (lane >> 4) << 4;
    int pA[8], pBf[4];
#pragma unroll
    for (int f = 0; f < 8; ++f) {
        int r = wm * 128 + f * 16 + (lane & 15);
        pA[f] = r * 128 + (((r ^ (r >> 3)) & 7) << 4);
    }
#pragma unroll
    for (int f = 0; f < 4; ++f) {
        int r = wn * 64 + f * 16 + (lane & 15);
        pBf[f] = r * 128 + (((r ^ (r >> 3)) & 7) << 4);
    }

    f32x4 acc[8][4] = {};
    bf16x8 bfr[4];
    // one phase: reads, staging, barrier, lgkm0+schedbar, 16 MFMA, barrier
    auto phase = [&](const char* bufA, const char* bufB, int q, int ksub,
                     bool readB, auto stage, bool vm0, bool vm8) {
        int kk = kb0 | (ksub << 6);
        if (readB) {
#pragma unroll
            for (int f = 0; f < 4; ++f)
                bfr[f] = *reinterpret_cast<const bf16x8*>(bufB + (pBf[f] ^ kk));
        }
        bf16x8 af[4];
#pragma unroll
        for (int f = 0; f < 4; ++f)
            af[f] = *reinterpret_cast<const bf16x8*>(bufA + (pA[q * 4 + f] ^ kk));
        stage();
        __builtin_amdgcn_s_barrier();
        asm volatile("s_waitcnt lgkmcnt(0)" ::: "memory");
        __builtin_amdgcn_sched_barrier(0);
        __builtin_amdgcn_s_setprio(1);
#pragma unroll
        for (int f = 0; f < 4; ++f)
#pragma unroll
            for (int nf = 0; nf < 4; ++nf)
                acc[q * 4 + f][nf] = __builtin_amdgcn_mfma_f32_16x16x32_bf16(
                    af[f], bfr[nf], acc[q * 4 + f][nf], 0, 0, 0);
        __builtin_amdgcn_s_setprio(0);
        if (vm0) asm volatile("s_waitcnt vmcnt(0)" ::: "memory");
        if (vm8) asm volatile("s_waitcnt vmcnt(8)" ::: "memory");
        __builtin_amdgcn_s_barrier();
        __builtin_amdgcn_sched_barrier(0);
    };
    auto nop = [&]() {};

    // ---- prologue: lA0=A(0), lB0=B(0); v=B(1) in flight
    stageA2(lA0, 0, 0); stageA2(lA0, 0, 1);
    loadB4(0, 0); loadB4(0, 1);
    cvtB(lB0);                       // reg-dep wait drains A(0)+B(0)
    loadB4(1, 0); loadB4(1, 1);
    asm volatile("s_waitcnt vmcnt(8) lgkmcnt(0)" ::: "memory");
    __builtin_amdgcn_s_barrier();

    int nIter = nkt >> 1;
    for (int i = 0; i < nIter; ++i) {
        int t0 = 2 * i;
        // ---- tile t0 on buffers 0
        phase(lA0, lB0, 0, 0, true,
              [&]() { cvtB(lB1); stageA2(lA1, t0 + 1, 0); }, false, false);
        phase(lA0, lB0, 1, 0, false,
              [&]() { stageA2(lA1, t0 + 1, 1); loadB4(t0 + 2, 0); }, false, false);
        phase(lA0, lB0, 0, 1, true,
              [&]() { loadB4(t0 + 2, 1); }, false, false);
        phase(lA0, lB0, 1, 1, false, nop, true, false);   // vmcnt(0)
        // ---- tile t0+1 on buffers 1
        phase(lA1, lB1, 0, 0, true,
              [&]() { cvtB(lB0); stageA2(lA0, t0 + 2, 0); }, false, false);
        phase(lA1, lB1, 1, 0, false,
              [&]() { stageA2(lA0, t0 + 2, 1); }, false, false);
        phase(lA1, lB1, 0, 1, true,
              [&]() { loadB4(t0 + 3, 0); }, false, false);
        phase(lA1, lB1, 1, 1, false,
              [&]() { loadB4(t0 + 3, 1); }, false, true);  // vmcnt(8)
    }
    if (nkt & 1) {                   // tail tile nkt-1: lA0/lB0 ready
        phase(lA0, lB0, 0, 0, true,  nop, false, false);
        phase(lA0, lB0, 1, 0, false, nop, false, false);
        phase(lA0, lB0, 0, 1, true,  nop, false, false);
        phase(lA0, lB0, 1, 1, false, nop, false, false);
    }

    float* outp = Cp + (size_t)ks * Mtot * N;
    int rb0 = m0 + wm * 128;
    int cb = n0 + wn * 64 + (lane & 15);
    int rl = (lane >> 4) * 4;
#pragma unroll
    for (int mf = 0; mf < 8; ++mf)
#pragma unroll
        for (int nf = 0; nf < 4; ++nf)
#pragma unroll
            for (int r = 0; r < 4; ++r)
                outp[(size_t)(rb0 + mf * 16 + rl + r) * N + cb + nf * 16] =
                    acc[mf][nf][r];
}

// ---------------------------------------------------------------------------
// 128x128 counted-wait kernel (R10 structure) — head GEMM only (N=128).
// Requires nkt >= 3.
// ---------------------------------------------------------------------------
__global__ __launch_bounds__(256, 2) void gemm_f32b_kernel(
        const __hip_bfloat16* __restrict__ A,
        const float* __restrict__ Bf,
        float* __restrict__ Cp,
        int N, int lda, int ldbn, int kChunk, int nMT, int nNT, int Mtot,
        int perm) {
    __shared__ __align__(16) char lA[3 * 16384];
    __shared__ __align__(16) char lB[2 * 16384];

    int q = gridDim.x >> 3;
    int bid = (blockIdx.x & 7) * q + (blockIdx.x >> 3);
    int mt = bid % nMT;
    int nt = (bid / nMT) % nNT;
    int ks = bid / (nMT * nNT);
    int m0 = mt * 128, n0 = nt * 128;
    int k0 = ks * kChunk;
    int t = threadIdx.x;
    int lane = t & 63, wid = t >> 6;

    const char* srcA[4]; int offA[4];
#pragma unroll
    for (int i = 0; i < 4; ++i) {
        int chunk = i * 4 + wid;
        int p = chunk * 1024 + lane * 16;
        int row = p >> 7;
        int swz = ((row ^ (row >> 3)) & 7) << 4;
        srcA[i] = (const char*)A + ((size_t)(m0 + row) * lda + k0) * 2
                  + ((p & 127) ^ swz);
        offA[i] = chunk * 1024;
    }
    auto stageA = [&](char* slot) {
#pragma unroll
        for (int i = 0; i < 4; ++i) {
            gload_lds16(srcA[i], slot + offA[i]);
            srcA[i] += 128;
        }
    };

    int n4 = (t & 31) * 4;
    int k8 = (t >> 5) * 8;
    int rstr = perm ? 49 : 1;
    const float* pB = Bf + n0 + n4;
    int koff[8];
#pragma unroll
    for (int p = 0; p < 8; ++p) koff[p] = (k8 + p) * rstr * ldbn;
    int woff[4];
#pragma unroll
    for (int j = 0; j < 4; ++j) {
        int row = n4 + j;
        int swz = ((row ^ (row >> 3)) & 7) << 4;
        woff[j] = row * 128 + ((k8 * 2) ^ swz);
    }
    auto loadB = [&](int kt, f32x4 (&v)[8]) {
        int kb = k0 + (kt << 6);
        int rb = perm ? ((kb & 511) * 49 + (kb >> 9)) : kb;
        int rbo = rb * ldbn;
#pragma unroll
        for (int p = 0; p < 8; ++p)
            v[p] = *reinterpret_cast<const f32x4*>(pB + (size_t)(rbo + koff[p]));
    };
    auto cvtB = [&](f32x4 (&v)[8], char* bW) {
#pragma unroll
        for (int j = 0; j < 4; ++j) {
            uint4 w;
            w.x = pack_bf16x2(v[0][j], v[1][j]);
            w.y = pack_bf16x2(v[2][j], v[3][j]);
            w.z = pack_bf16x2(v[4][j], v[5][j]);
            w.w = pack_bf16x2(v[6][j], v[7][j]);
            *reinterpret_cast<uint4*>(bW + woff[j]) = w;
        }
    };

    int wm = wid >> 1, wn = wid & 1;
    int kb0 = (lane >> 4) << 4;
    int roA[4], roB[4], sA[4], sB[4];
#pragma unroll
    for (int f = 0; f < 4; ++f) {
        int ra = wm * 64 + f * 16 + (lane & 15);
        int rb = wn * 64 + f * 16 + (lane & 15);
        roA[f] = ra * 128; sA[f] = ((ra ^ (ra >> 3)) & 7) << 4;
        roB[f] = rb * 128; sB[f] = ((rb ^ (rb >> 3)) & 7) << 4;
    }

    f32x4 acc[4][4] = {};
    auto mfmaHalf = [&](const char* bA, const char* bB, int ksub) {
        int kk = kb0 | (ksub << 6);
        bf16x8 af[4], bfr[4];
#pragma unroll
        for (int f = 0; f < 4; ++f)
            af[f] = *reinterpret_cast<const bf16x8*>(bA + roA[f] + (kk ^ sA[f]));
#pragma unroll
        for (int f = 0; f < 4; ++f)
            bfr[f] = *reinterpret_cast<const bf16x8*>(bB + roB[f] + (kk ^ sB[f]));
#pragma unroll
        for (int mf = 0; mf < 4; ++mf)
#pragma unroll
            for (int nf = 0; nf < 4; ++nf)
                acc[mf][nf] = __builtin_amdgcn_mfma_f32_16x16x32_bf16(
                    af[mf], bfr[nf], acc[mf][nf], 0, 0, 0);
    };

    int nkt = kChunk >> 6;
    f32x4 vP[8], vQ[8];
    auto body = [&](int tt, char* aR, char* aS,
                    f32x4 (&vC)[8], char* bR, char* bW) {
        mfmaHalf(aR, bR, 0);
        if (tt + 1 < nkt) cvtB(vC, bW);
        mfmaHalf(aR, bR, 1);
        if (tt + 2 < nkt) stageA(aS);
        if (tt + 3 < nkt) {
            loadB(tt + 3, vC);
            asm volatile("s_waitcnt vmcnt(12) lgkmcnt(0)\ns_barrier" ::: "memory");
        } else {
            asm volatile("s_waitcnt vmcnt(0) lgkmcnt(0)\ns_barrier" ::: "memory");
        }
    };

    stageA(lA);
    stageA(lA + 16384);
    loadB(0, vP);
    loadB(1, vQ);
    cvtB(vP, lB);
    loadB(2, vP);
    asm volatile("s_waitcnt vmcnt(12) lgkmcnt(0)\ns_barrier" ::: "memory");

    char* s0 = lA;  char* s1 = lA + 16384;  char* s2 = lA + 32768;
    char* b0 = lB;  char* b1 = lB + 16384;
    for (int kt = 0; kt < nkt; kt += 6) {
        body(kt + 0, s0, s2, vQ, b0, b1);
        if (kt + 1 < nkt) body(kt + 1, s1, s0, vP, b1, b0);
        if (kt + 2 < nkt) body(kt + 2, s2, s1, vQ, b0, b1);
        if (kt + 3 < nkt) body(kt + 3, s0, s2, vP, b1, b0);
        if (kt + 4 < nkt) body(kt + 4, s1, s0, vQ, b0, b1);
        if (kt + 5 < nkt) body(kt + 5, s2, s1, vP, b1, b0);
    }

    float* outp = Cp + (size_t)ks * Mtot * N;
    int rbase = m0 + wm * 64;
    int cbase = n0 + wn * 64 + (lane & 15);
    int rl = (lane >> 4) * 4;
#pragma unroll
    for (int mf = 0; mf < 4; ++mf)
#pragma unroll
        for (int nf = 0; nf < 4; ++nf)
#pragma unroll
            for (int r = 0; r < 4; ++r)
                outp[(size_t)(rbase + mf * 16 + rl + r) * N + cbase + nf * 16] =
                    acc[mf][nf][r];
}

// ---------------------------------------------------------------------------
// Sum KS split-K partials + bias, ReLU, convert to bf16.
// ---------------------------------------------------------------------------
__global__ __launch_bounds__(256) void reduce_bias_relu_kernel(
        const float* __restrict__ P, const float* __restrict__ bias,
        __hip_bfloat16* __restrict__ out, int MN, int N, int KS) {
    int idx = blockIdx.x * blockDim.x + threadIdx.x;
    int e0 = idx * 4;
    if (e0 >= MN) return;
    f32x4 s = *reinterpret_cast<const f32x4*>(P + e0);
    for (int k = 1; k < KS; ++k)
        s += *reinterpret_cast<const f32x4*>(P + (size_t)k * MN + e0);
    f32x4 b = *reinterpret_cast<const f32x4*>(bias + (e0 & (N - 1)));
    s += b;
    uint2 pk;
    pk.x = pack_bf16x2(fmaxf(s[0], 0.f), fmaxf(s[1], 0.f));
    pk.y = pack_bf16x2(fmaxf(s[2], 0.f), fmaxf(s[3], 0.f));
    *reinterpret_cast<uint2*>(reinterpret_cast<char*>(out) + (size_t)e0 * 2) = pk;
}

// ---------------------------------------------------------------------------
// Sum KS head partials + bias, scatter to (params, scores) output layout.
// ---------------------------------------------------------------------------
__global__ __launch_bounds__(128) void head_reduce_kernel(
        const float* __restrict__ P, const float* __restrict__ bp,
        const float* __restrict__ bs, float* __restrict__ out, int KS) {
    int n = blockIdx.x, c = threadIdx.x;
    float s = 0.f;
    for (int ks = 0; ks < KS; ++ks)
        s += P[(size_t)ks * NROI * 128 + (size_t)n * 128 + c];
    if (c < NPAR)
        out[(size_t)n * NPAR + c] = s + bp[c];
    else if (c < NPAR + NCLS)
        out[(size_t)NROI * NPAR + (size_t)n * NCLS + (c - NPAR)] = s + bs[c - NPAR];
}

// ---------------------------------------------------------------------------
extern "C" void kernel_launch(void* const* d_in, const int* in_sizes, int n_in,
                              void* d_out, int out_size, void* d_ws, size_t ws_size,
                              hipStream_t stream) {
    const float* x    = (const float*)d_in[0];
    const float* rois = (const float*)d_in[1];
    // d_in[2] roi_index: B=1 -> always 0, unused
    const float* W1 = (const float*)d_in[3];
    const float* b1 = (const float*)d_in[4];
    const float* W2 = (const float*)d_in[5];
    const float* b2 = (const float*)d_in[6];
    const float* Wp = (const float*)d_in[7];
    const float* bp = (const float*)d_in[8];
    const float* Ws = (const float*)d_in[9];
    const float* bs = (const float*)d_in[10];
    float* out = (float*)d_out;

    const size_t MB = 1ull << 20;
    char* ws = (char*)d_ws;
    float*          xt     = (float*)(ws + 0);                  // 3.62 MB
    __hip_bfloat16* pooled = (__hip_bfloat16*)(ws + 4   * MB);  // 24.5 MB
    float*          Whp    = (float*)(ws + 30  * MB);           // 2 MB
    float*          part   = (float*)(ws + 34  * MB);           // 64 MB (KS=8)
    __hip_bfloat16* fc6    = (__hip_bfloat16*)(ws + 104 * MB);  // 4 MB
    __hip_bfloat16* fc7    = (__hip_bfloat16*)(ws + 109 * MB);  // 4 MB

    prep_kernel<<<PB_TOT, 256, 0, stream>>>(x, xt, Wp, Ws, Whp);
    roi_pool_kernel<<<NROI, 256, 0, stream>>>(xt, rois, pooled);

    // fc6 = relu(pooled @ W1 + b1): M=512 N=4096 K=25088; 256 blocks, KS=8
    gemm256_kernel<<<2 * 16 * KS1, 512, 0, stream>>>(
        pooled, W1, part, DFC, DIN, DFC, DIN / KS1, 2, 16, NROI, 1);
    reduce_bias_relu_kernel<<<2048, 256, 0, stream>>>(part, b1, fc6,
                                                      NROI * DFC, DFC, KS1);

    // fc7 = relu(fc6 @ W2 + b2): M=512 N=4096 K=4096; 256 blocks, KS=8
    gemm256_kernel<<<2 * 16 * KS2, 512, 0, stream>>>(
        fc6, W2, part, DFC, DFC, DFC, DFC / KS2, 2, 16, NROI, 0);
    reduce_bias_relu_kernel<<<2048, 256, 0, stream>>>(part, b2, fc7,
                                                      NROI * DFC, DFC, KS2);

    // head = fc7 @ [Wp|Ws]: M=512 N=128(pad from 105) K=4096, KS=8 (nkt=8)
    gemm_f32b_kernel<<<4 * KSH, 256, 0, stream>>>(fc7, Whp, part,
                                                  128, DFC, 128, DFC / KSH,
                                                  4, 1, NROI, 0);
    head_reduce_kernel<<<NROI, 128, 0, stream>>>(part, bp, bs, out, KSH);
}